// Round 6
// baseline (2644.910 us; speedup 1.0000x reference)
//
#include <hip/hip_runtime.h>
#include <hip/hip_bf16.h>

typedef unsigned short u16;
typedef unsigned long long u64;
typedef __attribute__((ext_vector_type(8))) short bf16x8;   // 8 bf16 in 4 VGPRs
typedef __attribute__((ext_vector_type(4))) float f32x4;    // MFMA acc

#define MFMA16(a, b, c) __builtin_amdgcn_mfma_f32_16x16x32_bf16((a), (b), (c), 0, 0, 0)

static constexpr int Ee = 300, EP = 320, Hh = 1024, G3 = 3072;
static constexpr int Bb = 64, Tt = 512;

// workspace layout (bytes)
static constexpr long OFF_GX   = 0L;                      // [512][3072][64] bf16 = 201326592
static constexpr long OFF_EMB  = 201326592L;              // [32768][320] bf16   = 20971520
static constexpr long OFF_WIH  = 222298112L;              // [3072][320] bf16    = 1966080
static constexpr long OFF_WHH  = 224264192L;              // [3072][1024] bf16   = 6291456
static constexpr long OFF_HBUF = 230555648L;              // 4 grp x 2 x [16][1024] bf16

__device__ __forceinline__ u16 f2bf(float f) {
    union { float f; unsigned u; } v; v.f = f;
    unsigned u = v.u;
    return (u16)((u + 0x7fffu + ((u >> 16) & 1u)) >> 16);   // RNE
}
__device__ __forceinline__ float bf2f(u16 u) {
    union { unsigned u; float f; } v; v.u = ((unsigned)u) << 16;
    return v.f;
}
__device__ __forceinline__ float fast_sigmoid(float x) {
    return 1.f / (1.f + __expf(-x));
}
__device__ __forceinline__ float fast_tanh(float x) {
    float ax = fabsf(x);
    float e = __expf(-2.f * ax);
    float t = (1.f - e) / (1.f + e);
    return copysignf(t, x);
}

// ---------------------------------------------------------------- prep ------
static constexpr long R0 = (long)Bb * Tt * EP;   // emb gather (bf16, padded)
static constexpr long R1 = (long)G3 * EP;        // W_ih -> bf16 padded
static constexpr long R2 = (long)G3 * Hh;        // W_hh -> bf16
static constexpr long R3 = 131072;               // h buffers (4 grp x 2 slots x 16384 u16)
static constexpr long R4 = 320;                  // out = bias (d_out is poisoned!)

__global__ void prep_kernel(const int* __restrict__ x, const float* __restrict__ emb,
                            const float* __restrict__ wih, const float* __restrict__ whh,
                            const float* __restrict__ bfc,
                            u16* __restrict__ emb_bf, u16* __restrict__ wih_bf,
                            u16* __restrict__ whh_bf, u16* __restrict__ h0,
                            float* __restrict__ out) {
    const long total = R0 + R1 + R2 + R3 + R4;
    for (long i = (long)blockIdx.x * blockDim.x + threadIdx.x; i < total;
         i += (long)gridDim.x * blockDim.x) {
        if (i < R0) {
            const int m = (int)(i / EP), k = (int)(i % EP);
            const int b = m & 63, t = m >> 6;
            u16 v = 0;
            if (k < Ee) {
                const int xi = x[b * Tt + t];
                v = f2bf(emb[(size_t)xi * Ee + k]);
            }
            emb_bf[i] = v;
        } else if (i < R0 + R1) {
            const long j = i - R0;
            const int k = (int)(j % EP);
            const int n = (int)(j / EP);
            wih_bf[j] = (k < Ee) ? f2bf(wih[(size_t)n * Ee + k]) : (u16)0;
        } else if (i < R0 + R1 + R2) {
            const long j = i - R0 - R1;
            whh_bf[j] = f2bf(whh[j]);
        } else if (i < R0 + R1 + R2 + R3) {
            // h slots: slot0 = h_0 = 0 (tag 0 matches step 0); slot1 pre-filled
            // with tag bit 1 (u16 index % 4 == 0 carries the tag) so step-1
            // consumers block until real h_1 (tag 0) arrives.
            const long idx = i - R0 - R1 - R2;
            const int slot = (int)((idx >> 14) & 1);
            h0[idx] = (slot == 1 && (idx & 3) == 0) ? (u16)1 : (u16)0;
        } else {
            const long j = i - R0 - R1 - R2 - R3;
            out[j] = bfc[j % 5];
        }
    }
}

// ------------------------------------------------------------- gx GEMM ------
// gx[t][n][b] = sum_k emb_bf[m=t*64+b][k] * wih_bf[n][k] + b_ih[n], bf16 out.
__global__ __launch_bounds__(256, 2)
void gx_gemm(const u16* __restrict__ A, const u16* __restrict__ Bm,
             const float* __restrict__ bih, u16* __restrict__ gx) {
    __shared__ __align__(16) u16 lA[128 * 32];
    __shared__ __align__(16) u16 lB[128 * 32];
    const int tid = threadIdx.x;
    const int lane = tid & 63;
    const int wv = tid >> 6;
    const int quad = lane >> 4, l15 = lane & 15;
    const int m0 = blockIdx.x * 128;
    const int n0 = blockIdx.y * 128;
    const int mo = (wv & 1) * 64, no = (wv >> 1) * 64;
    const int srow = tid >> 2;
    const int sseg = tid & 3;

    f32x4 acc[4][4] = {};

    for (int s = 0; s < 10; ++s) {
        const int k0 = s * 32;
        __syncthreads();
#pragma unroll
        for (int p = 0; p < 2; ++p) {
            const u16* ga = A + (size_t)(m0 + p * 64 + srow) * EP + k0 + sseg * 8;
            u16* la = &lA[p * 2048 + wv * 512];
            __builtin_amdgcn_global_load_lds(
                (const __attribute__((address_space(1))) void*)ga,
                (__attribute__((address_space(3))) void*)la, 16, 0, 0);
            const u16* gb = Bm + (size_t)(n0 + p * 64 + srow) * EP + k0 + sseg * 8;
            u16* lb = &lB[p * 2048 + wv * 512];
            __builtin_amdgcn_global_load_lds(
                (const __attribute__((address_space(1))) void*)gb,
                (__attribute__((address_space(3))) void*)lb, 16, 0, 0);
        }
        __syncthreads();

        bf16x8 af[4], bfr[4];
#pragma unroll
        for (int mt = 0; mt < 4; ++mt)
            af[mt] = *(const bf16x8*)&lA[(mo + mt * 16 + l15) * 32 + quad * 8];
#pragma unroll
        for (int nt = 0; nt < 4; ++nt)
            bfr[nt] = *(const bf16x8*)&lB[(no + nt * 16 + l15) * 32 + quad * 8];
#pragma unroll
        for (int mt = 0; mt < 4; ++mt)
#pragma unroll
            for (int nt = 0; nt < 4; ++nt)
                acc[mt][nt] = MFMA16(af[mt], bfr[nt], acc[mt][nt]);
    }

    // C layout: row m = quad*4+r, col n = lane&15
#pragma unroll
    for (int mt = 0; mt < 4; ++mt) {
        const int mg = m0 + mo + mt * 16 + quad * 4;
        const int t = mg >> 6, b0 = mg & 63;
#pragma unroll
        for (int nt = 0; nt < 4; ++nt) {
            const int n = n0 + no + nt * 16 + l15;
            const float bi = bih[n];
            ushort4 vv;
            vv.x = f2bf(acc[mt][nt][0] + bi);
            vv.y = f2bf(acc[mt][nt][1] + bi);
            vv.z = f2bf(acc[mt][nt][2] + bi);
            vv.w = f2bf(acc[mt][nt][3] + bi);
            *(ushort4*)&gx[((size_t)t * G3 + n) * 64 + b0] = vv;
        }
    }
}

// ---------------------------------------------------------------- scan ------
// 128 blocks x 512 thr = 4 independent batch groups x 32 col blocks. NO
// barriers/flags between blocks: each exchanged u64 (4 bf16 h) carries a step
// tag in bit0 of its low u16; producers fire-and-forget agent-scope stores,
// consumers poll the data itself until tag == (t>>1)&1. Slot = t&1; tag
// alternates per slot reuse. Causality: h_{t+1} is computed only from fully
// arrived h_t, so slot reuse (t vs t-2) can never be observed stale-fresh.
__global__ __launch_bounds__(512, 2)
void scan_kernel(const u16* __restrict__ whh, const float* __restrict__ bhh,
                 const u16* __restrict__ gx, u16* __restrict__ hbuf,
                 const float* __restrict__ wfc, float* __restrict__ out) {
    __shared__ __align__(16) u16 lh[16 * 1032];          // staged h (row stride 258 u64)
    __shared__ __align__(16) float red[2][3][4][16 * 20]; // [nh][g][kq][m*20+n]

    const int bid = blockIdx.x;
    const int bg = bid >> 5;          // batch group 0..3 (rows 16bg..+16)
    const int cg = bid & 31;          // col group 0..31 (cols 32cg..+32)
    const int w = threadIdx.x >> 6;   // wave 0..7
    const int lane = threadIdx.x & 63;
    const int kq = w & 3;             // K-quarter
    const int nh = w >> 2;            // col-half
    const int quad = lane >> 4, l15 = lane & 15;
    const int c0 = cg * 32;
    const bool isGate = (w == 3) || (w == 4);
    const int gnh = (w == 3) ? 0 : 1;

    // register-resident W: B-frag for col c0+nh*16+l15, gate g, k-chunk kq*8+s
    bf16x8 wf[3][8];
#pragma unroll
    for (int g = 0; g < 3; ++g) {
        const size_t rbase = (size_t)(g * 1024 + c0 + nh * 16 + l15) * 1024;
#pragma unroll
        for (int s = 0; s < 8; ++s)
            wf[g][s] = *(const bf16x8*)&whh[rbase + (kq * 8 + s) * 32 + quad * 8];
    }

    // gate-wave per-lane state: (b = bg*16+l15, j = c0+gnh*16+quad*4+jj)
    float bh[3][4];
    u16 gxv[3][4];
    float hO[4] = {0.f, 0.f, 0.f, 0.f};
    if (isGate) {
#pragma unroll
        for (int g = 0; g < 3; ++g)
#pragma unroll
            for (int jj = 0; jj < 4; ++jj) {
                const int jglob = c0 + gnh * 16 + quad * 4 + jj;
                bh[g][jj] = bhh[g * 1024 + jglob];
                gxv[g][jj] = gx[((size_t)g * 1024 + jglob) * 64 + bg * 16 + l15];
            }
    }

    u64* hbq = (u64*)hbuf + (size_t)bg * 8192;   // group base (2 slots x 4096 u64)
    const int srow = threadIdx.x >> 5;            // 0..15 (staging row)
    const int scol = threadIdx.x & 31;            // 32 threads/row, 256 u64/row
    u64* lhq = (u64*)lh;

    for (int t = 0; t < 512; ++t) {
        const u64* hcq = hbq + (t & 1) * 4096;
        u16* hn = hbuf + (size_t)bg * 32768 + ((t + 1) & 1) * 16384;
        const unsigned et = (unsigned)((t >> 1) & 1);

        // cooperative poll+stage: 8 u64/thread, re-poll only stale ones
        u64 stg[8];
        unsigned need = 0xFFu;
        while (need) {
            unsigned got = 0;
#pragma unroll
            for (int r = 0; r < 8; ++r) {
                if (need & (1u << r)) {
                    u64 v = __hip_atomic_load(&hcq[srow * 256 + scol + 32 * r],
                                              __ATOMIC_RELAXED, __HIP_MEMORY_SCOPE_AGENT);
                    stg[r] = v;
                    if ((unsigned)(v & 1ull) == et) got |= 1u << r;
                }
            }
            need &= ~got;
        }
#pragma unroll
        for (int r = 0; r < 8; ++r)
            lhq[srow * 258 + scol + 32 * r] = stg[r];
        __syncthreads();                      // sync1: lh ready

        // MFMA over this wave's K-quarter, 3 gates
        bf16x8 af[8];
#pragma unroll
        for (int s = 0; s < 8; ++s)
            af[s] = *(const bf16x8*)&lh[l15 * 1032 + kq * 256 + s * 32 + quad * 8];
        f32x4 acc[3] = {};
#pragma unroll
        for (int s = 0; s < 8; ++s) {
            acc[0] = MFMA16(af[s], wf[0][s], acc[0]);
            acc[1] = MFMA16(af[s], wf[1][s], acc[1]);
            acc[2] = MFMA16(af[s], wf[2][s], acc[2]);
        }
        // transposed red store [m*20+n]: m=quad*4+r, n=l15 -> 2-way max (free)
#pragma unroll
        for (int g = 0; g < 3; ++g)
#pragma unroll
            for (int r = 0; r < 4; ++r)
                red[nh][g][kq][(quad * 4 + r) * 20 + l15] = acc[g][r];
        __syncthreads();                      // sync2: red ready

        f32x4 rr[3][4];
        if (isGate) {
#pragma unroll
            for (int g = 0; g < 3; ++g)
#pragma unroll
                for (int k = 0; k < 4; ++k)
                    rr[g][k] = *(const f32x4*)&red[gnh][g][k][l15 * 20 + quad * 4];
        }
        __syncthreads();                      // sync3: red consumed; next stage may run

        if (isGate) {
            const unsigned wtag = (unsigned)(((t + 1) >> 1) & 1);
            u64 pack = 0;
#pragma unroll
            for (int jj = 0; jj < 4; ++jj) {
                const float s0 = rr[0][0][jj] + rr[0][1][jj] + rr[0][2][jj] + rr[0][3][jj];
                const float s1 = rr[1][0][jj] + rr[1][1][jj] + rr[1][2][jj] + rr[1][3][jj];
                const float s2 = rr[2][0][jj] + rr[2][1][jj] + rr[2][2][jj] + rr[2][3][jj];
                const float rg = fast_sigmoid(bf2f(gxv[0][jj]) + s0 + bh[0][jj]);
                const float zg = fast_sigmoid(bf2f(gxv[1][jj]) + s1 + bh[1][jj]);
                const float ng = fast_tanh(bf2f(gxv[2][jj]) + rg * (s2 + bh[2][jj]));
                const float hv = (1.f - zg) * ng + zg * hO[jj];
                hO[jj] = hv;
                u16 hb16 = f2bf(hv);
                if (jj == 0) hb16 = (u16)((hb16 & ~1u) | wtag);   // embed tag
                pack |= (u64)hb16 << (jj * 16);
            }
            // fire-and-forget: consumers poll the tag in the data itself
            __hip_atomic_store((u64*)&hn[l15 * 1024 + c0 + gnh * 16 + quad * 4],
                               pack, __ATOMIC_RELAXED, __HIP_MEMORY_SCOPE_AGENT);
            // prefetch next step's gx (read-only, off critical path)
            if (t < 511) {
#pragma unroll
                for (int g = 0; g < 3; ++g)
#pragma unroll
                    for (int jj = 0; jj < 4; ++jj)
                        gxv[g][jj] = gx[((size_t)(t + 1) * G3 + g * 1024 + c0 +
                                         gnh * 16 + quad * 4 + jj) * 64 + bg * 16 + l15];
            }
        }
    }

    // FC head from gate-wave registers: hO[jj] = h_T(b=bg*16+l15, j)
    if (isGate) {
#pragma unroll
        for (int p = 0; p < 5; ++p) {
            float v = 0.f;
#pragma unroll
            for (int jj = 0; jj < 4; ++jj)
                v += hO[jj] * wfc[p * 1024 + c0 + gnh * 16 + quad * 4 + jj];
            v += __shfl_xor(v, 16);
            v += __shfl_xor(v, 32);
            if (quad == 0)
                atomicAdd(&out[(bg * 16 + l15) * 5 + p], v);
        }
    }
}

// --------------------------------------------------------------- launch -----
extern "C" void kernel_launch(void* const* d_in, const int* in_sizes, int n_in,
                              void* d_out, int out_size, void* d_ws, size_t ws_size,
                              hipStream_t stream) {
    const int*   x   = (const int*)d_in[0];
    const float* emb = (const float*)d_in[1];
    const float* wih = (const float*)d_in[2];
    const float* whh = (const float*)d_in[3];
    const float* bih = (const float*)d_in[4];
    const float* bhh = (const float*)d_in[5];
    const float* wfc = (const float*)d_in[6];
    const float* bfc = (const float*)d_in[7];
    float* out = (float*)d_out;

    char* ws = (char*)d_ws;
    u16*   gxw   = (u16*)(ws + OFF_GX);
    u16*   embbf = (u16*)(ws + OFF_EMB);
    u16*   wihbf = (u16*)(ws + OFF_WIH);
    u16*   whhbf = (u16*)(ws + OFF_WHH);
    u16*   hbuf  = (u16*)(ws + OFF_HBUF);

    prep_kernel<<<8192, 256, 0, stream>>>(x, emb, wih, whh, bfc, embbf, wihbf,
                                          whhbf, hbuf, out);

    gx_gemm<<<dim3(256, 24), 256, 0, stream>>>(embbf, wihbf, bih, gxw);

    scan_kernel<<<128, 512, 0, stream>>>(whhbf, bhh, gxw, hbuf, wfc, out);
}

// Round 7
// 2125.838 us; speedup vs baseline: 1.2442x; 1.2442x over previous
//
#include <hip/hip_runtime.h>
#include <hip/hip_bf16.h>

typedef unsigned short u16;
typedef unsigned long long u64;
typedef __attribute__((ext_vector_type(8))) short bf16x8;   // 8 bf16 in 4 VGPRs
typedef __attribute__((ext_vector_type(4))) float f32x4;    // MFMA acc

#define MFMA16(a, b, c) __builtin_amdgcn_mfma_f32_16x16x32_bf16((a), (b), (c), 0, 0, 0)

static constexpr int Ee = 300, EP = 320, Hh = 1024, G3 = 3072;
static constexpr int Bb = 64, Tt = 512;

// workspace layout (bytes)
static constexpr long OFF_GX   = 0L;                      // [512][3072][64] bf16 = 201326592
static constexpr long OFF_EMB  = 201326592L;              // [32768][320] bf16   = 20971520
static constexpr long OFF_WIH  = 222298112L;              // [3072][320] bf16    = 1966080
static constexpr long OFF_WHH  = 224264192L;              // [3072][1024] bf16   = 6291456
static constexpr long OFF_HBUF = 230555648L;              // 4 grp x 2 x [16][1024] bf16
static constexpr long OFF_FLAG = 230817792L;              // 4 grp x 64 flags x 64B

__device__ __forceinline__ u16 f2bf(float f) {
    union { float f; unsigned u; } v; v.f = f;
    unsigned u = v.u;
    return (u16)((u + 0x7fffu + ((u >> 16) & 1u)) >> 16);   // RNE
}
__device__ __forceinline__ float bf2f(u16 u) {
    union { unsigned u; float f; } v; v.u = ((unsigned)u) << 16;
    return v.f;
}
__device__ __forceinline__ float fast_sigmoid(float x) {
    return 1.f / (1.f + __expf(-x));
}
__device__ __forceinline__ float fast_tanh(float x) {
    float ax = fabsf(x);
    float e = __expf(-2.f * ax);
    float t = (1.f - e) / (1.f + e);
    return copysignf(t, x);
}

// ---------------------------------------------------------------- prep ------
static constexpr long R0 = (long)Bb * Tt * EP;   // emb gather (bf16, padded)
static constexpr long R1 = (long)G3 * EP;        // W_ih -> bf16 padded
static constexpr long R2 = (long)G3 * Hh;        // W_hh -> bf16
static constexpr long R3 = 131072;               // h buffers = 0
static constexpr long R4 = 4096;                 // flags = 0 (4 grp x 64 x 16 int)
static constexpr long R5 = 320;                  // out = bias (d_out is poisoned!)

__global__ void prep_kernel(const int* __restrict__ x, const float* __restrict__ emb,
                            const float* __restrict__ wih, const float* __restrict__ whh,
                            const float* __restrict__ bfc,
                            u16* __restrict__ emb_bf, u16* __restrict__ wih_bf,
                            u16* __restrict__ whh_bf, u16* __restrict__ h0,
                            int* __restrict__ flags, float* __restrict__ out) {
    const long total = R0 + R1 + R2 + R3 + R4 + R5;
    for (long i = (long)blockIdx.x * blockDim.x + threadIdx.x; i < total;
         i += (long)gridDim.x * blockDim.x) {
        if (i < R0) {
            const int m = (int)(i / EP), k = (int)(i % EP);
            const int b = m & 63, t = m >> 6;
            u16 v = 0;
            if (k < Ee) {
                const int xi = x[b * Tt + t];
                v = f2bf(emb[(size_t)xi * Ee + k]);
            }
            emb_bf[i] = v;
        } else if (i < R0 + R1) {
            const long j = i - R0;
            const int k = (int)(j % EP);
            const int n = (int)(j / EP);
            wih_bf[j] = (k < Ee) ? f2bf(wih[(size_t)n * Ee + k]) : (u16)0;
        } else if (i < R0 + R1 + R2) {
            const long j = i - R0 - R1;
            whh_bf[j] = f2bf(whh[j]);
        } else if (i < R0 + R1 + R2 + R3) {
            h0[i - R0 - R1 - R2] = 0;
        } else if (i < R0 + R1 + R2 + R3 + R4) {
            flags[i - R0 - R1 - R2 - R3] = 0;
        } else {
            const long j = i - R0 - R1 - R2 - R3 - R4;
            out[j] = bfc[j % 5];
        }
    }
}

// ------------------------------------------------------------- gx GEMM ------
// gx[t][n][b] = sum_k emb_bf[m=t*64+b][k] * wih_bf[n][k] + b_ih[n], bf16 out.
__global__ __launch_bounds__(256, 2)
void gx_gemm(const u16* __restrict__ A, const u16* __restrict__ Bm,
             const float* __restrict__ bih, u16* __restrict__ gx) {
    __shared__ __align__(16) u16 lA[128 * 32];
    __shared__ __align__(16) u16 lB[128 * 32];
    const int tid = threadIdx.x;
    const int lane = tid & 63;
    const int wv = tid >> 6;
    const int quad = lane >> 4, l15 = lane & 15;
    const int m0 = blockIdx.x * 128;
    const int n0 = blockIdx.y * 128;
    const int mo = (wv & 1) * 64, no = (wv >> 1) * 64;
    const int srow = tid >> 2;
    const int sseg = tid & 3;

    f32x4 acc[4][4] = {};

    for (int s = 0; s < 10; ++s) {
        const int k0 = s * 32;
        __syncthreads();
#pragma unroll
        for (int p = 0; p < 2; ++p) {
            const u16* ga = A + (size_t)(m0 + p * 64 + srow) * EP + k0 + sseg * 8;
            u16* la = &lA[p * 2048 + wv * 512];
            __builtin_amdgcn_global_load_lds(
                (const __attribute__((address_space(1))) void*)ga,
                (__attribute__((address_space(3))) void*)la, 16, 0, 0);
            const u16* gb = Bm + (size_t)(n0 + p * 64 + srow) * EP + k0 + sseg * 8;
            u16* lb = &lB[p * 2048 + wv * 512];
            __builtin_amdgcn_global_load_lds(
                (const __attribute__((address_space(1))) void*)gb,
                (__attribute__((address_space(3))) void*)lb, 16, 0, 0);
        }
        __syncthreads();

        bf16x8 af[4], bfr[4];
#pragma unroll
        for (int mt = 0; mt < 4; ++mt)
            af[mt] = *(const bf16x8*)&lA[(mo + mt * 16 + l15) * 32 + quad * 8];
#pragma unroll
        for (int nt = 0; nt < 4; ++nt)
            bfr[nt] = *(const bf16x8*)&lB[(no + nt * 16 + l15) * 32 + quad * 8];
#pragma unroll
        for (int mt = 0; mt < 4; ++mt)
#pragma unroll
            for (int nt = 0; nt < 4; ++nt)
                acc[mt][nt] = MFMA16(af[mt], bfr[nt], acc[mt][nt]);
    }

    // C layout: row m = quad*4+r, col n = lane&15
#pragma unroll
    for (int mt = 0; mt < 4; ++mt) {
        const int mg = m0 + mo + mt * 16 + quad * 4;
        const int t = mg >> 6, b0 = mg & 63;
#pragma unroll
        for (int nt = 0; nt < 4; ++nt) {
            const int n = n0 + no + nt * 16 + l15;
            const float bi = bih[n];
            ushort4 vv;
            vv.x = f2bf(acc[mt][nt][0] + bi);
            vv.y = f2bf(acc[mt][nt][1] + bi);
            vv.z = f2bf(acc[mt][nt][2] + bi);
            vv.w = f2bf(acc[mt][nt][3] + bi);
            *(ushort4*)&gx[((size_t)t * G3 + n) * 64 + b0] = vv;
        }
    }
}

// ---------------------------------------------------------------- scan ------
// 128 blocks x 512 thr = 4 independent batch groups x 32 col blocks. Sync via
// per-producer done-flags: each gate wave stores its 64 packed u64 h values
// (agent scope -> MALL), drains its own vmcnt (wave-local s_waitcnt, no cache
// ops), lane0 stores flag=t+1. Consumers: every wave polls the group's 64
// flags (1/lane, stop-on-done, s_sleep backoff), then one-shot coalesced pull.
// Slot-reuse safety: producing h_{t+1} requires having consumed h_t (in-block
// syncthreads), so a writer of slot t&1 at step t+2 proves all readers of h_t
// are done (every consumer is a producer consumed by all).
__global__ __launch_bounds__(512, 2)
void scan_kernel(const u16* __restrict__ whh, const float* __restrict__ bhh,
                 const u16* __restrict__ gx, u16* __restrict__ hbuf,
                 const float* __restrict__ wfc, float* __restrict__ out,
                 int* __restrict__ flags) {
    __shared__ __align__(16) u16 lh[16 * 1032];           // staged h (row 258 u64)
    __shared__ __align__(16) float red[2][3][4][16 * 20]; // [nh][g][kq][m*20+n]

    const int bid = blockIdx.x;
    const int bg = bid >> 5;          // batch group 0..3 (rows 16bg..+16)
    const int cg = bid & 31;          // col group 0..31 (cols 32cg..+32)
    const int w = threadIdx.x >> 6;   // wave 0..7
    const int lane = threadIdx.x & 63;
    const int kq = w & 3;             // K-quarter
    const int nh = w >> 2;            // col-half
    const int quad = lane >> 4, l15 = lane & 15;
    const int c0 = cg * 32;
    const bool isGate = (w == 3) || (w == 4);
    const int gnh = (w == 3) ? 0 : 1;

    // register-resident W: B-frag for col c0+nh*16+l15, gate g, k-chunk kq*8+s
    bf16x8 wf[3][8];
#pragma unroll
    for (int g = 0; g < 3; ++g) {
        const size_t rbase = (size_t)(g * 1024 + c0 + nh * 16 + l15) * 1024;
#pragma unroll
        for (int s = 0; s < 8; ++s)
            wf[g][s] = *(const bf16x8*)&whh[rbase + (kq * 8 + s) * 32 + quad * 8];
    }

    // gate-wave per-lane state: (b = bg*16+l15, j = c0+gnh*16+quad*4+jj)
    float bh[3][4];
    u16 gxv[3][4];
    float hO[4] = {0.f, 0.f, 0.f, 0.f};
    if (isGate) {
#pragma unroll
        for (int g = 0; g < 3; ++g)
#pragma unroll
            for (int jj = 0; jj < 4; ++jj) {
                const int jglob = c0 + gnh * 16 + quad * 4 + jj;
                bh[g][jj] = bhh[g * 1024 + jglob];
                gxv[g][jj] = gx[((size_t)g * 1024 + jglob) * 64 + bg * 16 + l15];
            }
    }

    u64* hbq = (u64*)hbuf + (size_t)bg * 8192;   // group base (2 slots x 4096 u64)
    int* gflag = &flags[(bg * 64 + lane) * 16];  // this lane's polled flag
    int* myflag = &flags[(bg * 64 + cg * 2 + gnh) * 16];
    const int srow = threadIdx.x >> 5;            // staging row 0..15
    const int scol = threadIdx.x & 31;            // 32 thr/row, 256 u64/row
    u64* lhq = (u64*)lh;

    for (int t = 0; t < 512; ++t) {
        const u64* hcq = hbq + (t & 1) * 4096;
        u16* hn = hbuf + (size_t)bg * 32768 + ((t + 1) & 1) * 16384;

        // ---- poll per-producer flags (all waves; 1 flag per lane) ----
        {
            int v = __hip_atomic_load(gflag, __ATOMIC_RELAXED, __HIP_MEMORY_SCOPE_AGENT);
            bool done = (v >= t);
            while (!__all(done)) {
                __builtin_amdgcn_s_sleep(1);
                if (!done) {
                    v = __hip_atomic_load(gflag, __ATOMIC_RELAXED, __HIP_MEMORY_SCOPE_AGENT);
                    done = (v >= t);
                }
            }
            __asm__ volatile("" ::: "memory");   // keep data loads after poll
        }

        // ---- one-shot coalesced pull -> LDS ----
        u64 stg[8];
#pragma unroll
        for (int r = 0; r < 8; ++r)
            stg[r] = __hip_atomic_load(&hcq[srow * 256 + scol + 32 * r],
                                       __ATOMIC_RELAXED, __HIP_MEMORY_SCOPE_AGENT);
#pragma unroll
        for (int r = 0; r < 8; ++r)
            lhq[srow * 258 + scol + 32 * r] = stg[r];
        __syncthreads();                      // sync1: lh ready

        // MFMA over this wave's K-quarter, 3 gates
        bf16x8 af[8];
#pragma unroll
        for (int s = 0; s < 8; ++s)
            af[s] = *(const bf16x8*)&lh[l15 * 1032 + kq * 256 + s * 32 + quad * 8];
        f32x4 acc[3] = {};
#pragma unroll
        for (int s = 0; s < 8; ++s) {
            acc[0] = MFMA16(af[s], wf[0][s], acc[0]);
            acc[1] = MFMA16(af[s], wf[1][s], acc[1]);
            acc[2] = MFMA16(af[s], wf[2][s], acc[2]);
        }
        // transposed red store [m*20+n]: max 2-way conflict (free)
#pragma unroll
        for (int g = 0; g < 3; ++g)
#pragma unroll
            for (int r = 0; r < 4; ++r)
                red[nh][g][kq][(quad * 4 + r) * 20 + l15] = acc[g][r];
        __syncthreads();                      // sync2: red ready

        if (isGate) {
            f32x4 rr[3][4];
#pragma unroll
            for (int g = 0; g < 3; ++g)
#pragma unroll
                for (int k = 0; k < 4; ++k)
                    rr[g][k] = *(const f32x4*)&red[gnh][g][k][l15 * 20 + quad * 4];
            u64 pack = 0;
#pragma unroll
            for (int jj = 0; jj < 4; ++jj) {
                const float s0 = rr[0][0][jj] + rr[0][1][jj] + rr[0][2][jj] + rr[0][3][jj];
                const float s1 = rr[1][0][jj] + rr[1][1][jj] + rr[1][2][jj] + rr[1][3][jj];
                const float s2 = rr[2][0][jj] + rr[2][1][jj] + rr[2][2][jj] + rr[2][3][jj];
                const float rg = fast_sigmoid(bf2f(gxv[0][jj]) + s0 + bh[0][jj]);
                const float zg = fast_sigmoid(bf2f(gxv[1][jj]) + s1 + bh[1][jj]);
                const float ng = fast_tanh(bf2f(gxv[2][jj]) + rg * (s2 + bh[2][jj]));
                const float hv = (1.f - zg) * ng + zg * hO[jj];
                hO[jj] = hv;
                pack |= (u64)f2bf(hv) << (jj * 16);
            }
            if (t < 511) {
                // data store -> wave-local drain (ack at MALL) -> flag store
                __hip_atomic_store((u64*)&hn[l15 * 1024 + c0 + gnh * 16 + quad * 4],
                                   pack, __ATOMIC_RELAXED, __HIP_MEMORY_SCOPE_AGENT);
                __builtin_amdgcn_s_waitcnt(0);
                if (lane == 0)
                    __hip_atomic_store(myflag, t + 1, __ATOMIC_RELAXED,
                                       __HIP_MEMORY_SCOPE_AGENT);
                // prefetch next step's gx (read-only, off critical path)
#pragma unroll
                for (int g = 0; g < 3; ++g)
#pragma unroll
                    for (int jj = 0; jj < 4; ++jj)
                        gxv[g][jj] = gx[((size_t)(t + 1) * G3 + g * 1024 + c0 +
                                         gnh * 16 + quad * 4 + jj) * 64 + bg * 16 + l15];
            }
        }
    }

    // FC head from gate-wave registers: hO[jj] = h_T(b=bg*16+l15, j)
    if (isGate) {
#pragma unroll
        for (int p = 0; p < 5; ++p) {
            float v = 0.f;
#pragma unroll
            for (int jj = 0; jj < 4; ++jj)
                v += hO[jj] * wfc[p * 1024 + c0 + gnh * 16 + quad * 4 + jj];
            v += __shfl_xor(v, 16);
            v += __shfl_xor(v, 32);
            if (quad == 0)
                atomicAdd(&out[(bg * 16 + l15) * 5 + p], v);
        }
    }
}

// --------------------------------------------------------------- launch -----
extern "C" void kernel_launch(void* const* d_in, const int* in_sizes, int n_in,
                              void* d_out, int out_size, void* d_ws, size_t ws_size,
                              hipStream_t stream) {
    const int*   x   = (const int*)d_in[0];
    const float* emb = (const float*)d_in[1];
    const float* wih = (const float*)d_in[2];
    const float* whh = (const float*)d_in[3];
    const float* bih = (const float*)d_in[4];
    const float* bhh = (const float*)d_in[5];
    const float* wfc = (const float*)d_in[6];
    const float* bfc = (const float*)d_in[7];
    float* out = (float*)d_out;

    char* ws = (char*)d_ws;
    u16*   gxw   = (u16*)(ws + OFF_GX);
    u16*   embbf = (u16*)(ws + OFF_EMB);
    u16*   wihbf = (u16*)(ws + OFF_WIH);
    u16*   whhbf = (u16*)(ws + OFF_WHH);
    u16*   hbuf  = (u16*)(ws + OFF_HBUF);
    int*   flags = (int*)(ws + OFF_FLAG);

    prep_kernel<<<8192, 256, 0, stream>>>(x, emb, wih, whh, bfc, embbf, wihbf,
                                          whhbf, hbuf, flags, out);

    gx_gemm<<<dim3(256, 24), 256, 0, stream>>>(embbf, wihbf, bih, gxw);

    scan_kernel<<<128, 512, 0, stream>>>(whhbf, bhh, gxw, hbuf, wfc, out, flags);
}